// Round 3
// baseline (441.470 us; speedup 1.0000x reference)
//
#include <hip/hip_runtime.h>

// IndRNN recurrence: h_t = relu(h_{t-1} * w + x_t) elementwise over (B,H),
// sequential over T. Memory-bound: 512 MiB traffic, ~85 us floor at 6.3 TB/s.
//
// R1 post-mortem: 2.5 TB/s achieved. Limiter = in-flight read depth:
// need ~BW*latency = 10.25 B/cyc/CU * ~1500 cyc ~ 15 KB/CU; W=16 scalar gave
// exactly 16 KB nominal, less effectively (stores share the vmcnt queue).
// R2: float2 lanes + W=32 windows -> 32 KB/CU nominal in-flight reads;
// batch load -> batch compute -> batch store (waits never chase stores);
// nontemporal stores keep the 512 MiB output stream from evicting L3-warm x.

#define T_DIM 1024
#define B_DIM 64
#define H_DIM 1024
#define BH2 (B_DIM * H_DIM / 2)   // 32768 float2 elements per t-step
#define W 32                      // time-window depth

typedef float f2 __attribute__((ext_vector_type(2)));

__global__ __launch_bounds__(128) void indrnn_kernel(
    const f2* __restrict__ x,      // [T, BH2]
    const f2* __restrict__ w,      // [H/2]
    const f2* __restrict__ h0,     // [BH2]
    f2* __restrict__ out)          // [T, BH2]
{
    const int idx = blockIdx.x * 128 + threadIdx.x;   // float2-element index
    const f2 wv = w[idx & (H_DIM / 2 - 1)];
    f2 h = h0[idx];
    const f2* xp = x + idx;
    f2* op = out + idx;

    f2 buf[W];
    #pragma unroll
    for (int i = 0; i < W; ++i) buf[i] = xp[(size_t)i * BH2];

    for (int t0 = 0; t0 < T_DIM; t0 += W) {
        // Prefetch next window first (last iter re-reads window 0: dead, in-bounds).
        const int tp = (t0 + W < T_DIM) ? (t0 + W) : 0;
        f2 nbuf[W];
        #pragma unroll
        for (int i = 0; i < W; ++i) nbuf[i] = xp[(size_t)(tp + i) * BH2];

        // Consume current window into a result array (no stores interleaved).
        f2 res[W];
        #pragma unroll
        for (int i = 0; i < W; ++i) {
            h.x = fmaxf(fmaf(h.x, wv.x, buf[i].x), 0.0f);
            h.y = fmaxf(fmaf(h.y, wv.y, buf[i].y), 0.0f);
            res[i] = h;
        }

        // Batch nontemporal stores.
        #pragma unroll
        for (int i = 0; i < W; ++i)
            __builtin_nontemporal_store(res[i], op + (size_t)(t0 + i) * BH2);

        #pragma unroll
        for (int i = 0; i < W; ++i) buf[i] = nbuf[i];
    }
}

extern "C" void kernel_launch(void* const* d_in, const int* in_sizes, int n_in,
                              void* d_out, int out_size, void* d_ws, size_t ws_size,
                              hipStream_t stream) {
    const f2* x  = (const f2*)d_in[0];
    const f2* w  = (const f2*)d_in[1];
    const f2* h0 = (const f2*)d_in[2];
    f2* out = (f2*)d_out;
    indrnn_kernel<<<BH2 / 128, 128, 0, stream>>>(x, w, h0, out);
}